// Round 5
// baseline (9864.054 us; speedup 1.0000x reference)
//
#include <hip/hip_runtime.h>

typedef short s16x8 __attribute__((ext_vector_type(8)));
typedef short s16x4 __attribute__((ext_vector_type(4)));
typedef float f32x4 __attribute__((ext_vector_type(4)));

#define T_N 2048
#define B_N 64
#define H_N 256
#define I_N 256
#define HY_BYTES ((size_t)134217728)   // 4 * T * B * H

static __device__ __forceinline__ short f2bf(float f) {
    unsigned u = __builtin_bit_cast(unsigned, f);
    u += 0x7FFFu + ((u >> 16) & 1u);   // RNE
    return (short)(u >> 16);
}
static __device__ __forceinline__ float bf2f(short h) {
    unsigned u = ((unsigned)(unsigned short)h) << 16;
    return __builtin_bit_cast(float, u);
}
static __device__ __forceinline__ float e2c(float a) {
    return __builtin_amdgcn_exp2f(fminf(a, 126.0f));
}
static __device__ __forceinline__ s16x4 ntl4(const void* p) {
    return __builtin_nontemporal_load((const s16x4*)p);
}

#define C1 1.44269504088896340f   // log2(e)
#define C2 2.88539008177792681f   // 2*log2(e)

#define MFMA(a, b, c) __builtin_amdgcn_mfma_f32_16x16x32_bf16(a, b, c, 0, 0, 0)

// ---------------------------------------------------------------------------
// Phase 1: xg[t,b,n] = x[t,b,:] @ w_ih[n,:] + (b_ih[n]+b_hh[n]),  bf16 in
// MFMA C-fragment layout inside d_out (unchanged).
// ---------------------------------------------------------------------------
__global__ __launch_bounds__(512) void xg_gemm(
        const float* __restrict__ x, const float* __restrict__ w_ih,
        const float* __restrict__ b_ih, const float* __restrict__ b_hh,
        char* __restrict__ out)
{
    const int tid  = threadIdx.x;
    const int wave = tid >> 6;
    const int lane = tid & 63;
    const int l15  = lane & 15;
    const int kg   = lane >> 4;

    __shared__ short Blds[8192];

    const int m16 = blockIdx.x * 8 + wave;
    const int by  = blockIdx.y;
    const int n0  = by * 256;

    const float* xrow = x + (size_t)(m16 * 16 + l15) * I_N;

    f32x4 acc[16] = {};

#pragma unroll 1
    for (int ks = 0; ks < 8; ++ks) {
        __syncthreads();
#pragma unroll
        for (int h = 0; h < 2; ++h) {
            int nl = (tid >> 2) + h * 128;
            int c  = tid & 3;
            const float* wp = w_ih + (size_t)(n0 + nl) * I_N + ks * 32 + c * 8;
            f32x4 w0 = *(const f32x4*)(wp);
            f32x4 w1 = *(const f32x4*)(wp + 4);
            s16x8 bv;
            bv[0]=f2bf(w0[0]); bv[1]=f2bf(w0[1]); bv[2]=f2bf(w0[2]); bv[3]=f2bf(w0[3]);
            bv[4]=f2bf(w1[0]); bv[5]=f2bf(w1[1]); bv[6]=f2bf(w1[2]); bv[7]=f2bf(w1[3]);
            int dt = nl >> 4;
            int lp = (nl & 15) + 16 * c;
            *(s16x8*)(&Blds[(dt * 64 + lp) * 8]) = bv;
        }
        __syncthreads();
        const float* ap = xrow + ks * 32 + kg * 8;
        f32x4 a0 = *(const f32x4*)(ap);
        f32x4 a1 = *(const f32x4*)(ap + 4);
        s16x8 av;
        av[0]=f2bf(a0[0]); av[1]=f2bf(a0[1]); av[2]=f2bf(a0[2]); av[3]=f2bf(a0[3]);
        av[4]=f2bf(a1[0]); av[5]=f2bf(a1[1]); av[6]=f2bf(a1[2]); av[7]=f2bf(a1[3]);
#pragma unroll
        for (int dt = 0; dt < 16; ++dt) {
            s16x8 bv = *(const s16x8*)(&Blds[(dt * 64 + lane) * 8]);
            acc[dt] = MFMA(av, bv, acc[dt]);
        }
    }

    const int t = m16 >> 2;
    const int g = m16 & 3;
#pragma unroll
    for (int dt = 0; dt < 16; ++dt) {
        int tau = by * 16 + dt;
        int n   = tau * 16 + l15;
        float bias = b_ih[n] + b_hh[n];
        size_t base = (tau < 32)
            ? ((size_t)t * 65536 + (size_t)g * 16384 + (size_t)tau * 512)
            : (HY_BYTES + (size_t)t * 65536 + (size_t)g * 16384 + (size_t)(tau - 32) * 512);
        s16x4 o;
        o[0] = f2bf(acc[dt][0] + bias);
        o[1] = f2bf(acc[dt][1] + bias);
        o[2] = f2bf(acc[dt][2] + bias);
        o[3] = f2bf(acc[dt][3] + bias);
        *(s16x4*)(out + base + lane * 8) = o;
    }
}

// ---------------------------------------------------------------------------
// Phase 2: persistent recurrence, 4 WGs x 8 waves, one barrier per step.
// No per-step vmcnt drain: compiler's counted dependency waits cover xg/ws
// loads; h/c stores are cached (L2-ack) and are never waited on.
// Queue order per step: stores(T-1) -> ws upfront -> MFMA(+ws ring) ->
// xg prefetch(T+1) -> activation -> hlds write -> lgkm + barrier.
// ---------------------------------------------------------------------------
template<bool USE_WS>
__global__ __launch_bounds__(512)
__attribute__((amdgpu_waves_per_eu(2, 2)))
void lstm_rec(
        const float* __restrict__ h0, const float* __restrict__ c0,
        const float* __restrict__ w_hh, char* __restrict__ out,
        char* __restrict__ ws)
{
    const int g    = blockIdx.x;
    const int tid  = threadIdx.x;
    const int w    = tid >> 6;
    const int lane = tid & 63;
    const int l15  = lane & 15;
    const int kg   = lane >> 4;

    __shared__ short hlds[2][4096];  // double-buffered 16x256 bf16, swizzled (16 KB)
    __shared__ short wlds[65536];    // g-gate weights (128 KB)

    s16x8 wreg[4][8];       // i,f gates (unified-file regs)
    s16x8 wregO[2][8];      // o gates (fallback only; DCE'd when USE_WS)

#pragma unroll
    for (int d = 0; d < 8; ++d) {
        const int q = d >> 1, ct = d & 1;
        const int tau = 16 * q + 2 * w + ct;
        const float* wp = w_hh + (size_t)(tau * 16 + l15) * H_N;
#pragma unroll
        for (int ks = 0; ks < 8; ++ks) {
            const float* p = wp + ks * 32 + kg * 8;
            f32x4 w0 = *(const f32x4*)(p);
            f32x4 w1 = *(const f32x4*)(p + 4);
            s16x8 v;
            v[0]=f2bf(w0[0]); v[1]=f2bf(w0[1]); v[2]=f2bf(w0[2]); v[3]=f2bf(w0[3]);
            v[4]=f2bf(w1[0]); v[5]=f2bf(w1[1]); v[6]=f2bf(w1[2]); v[7]=f2bf(w1[3]);
            if (d < 4) {
                wreg[d][ks] = v;
            } else if (d < 6) {
                *(s16x8*)(&wlds[(((w * 2 + (d - 4)) * 8 + ks) * 64 + lane) * 8]) = v;
            } else {
                if constexpr (USE_WS) {
                    *(s16x8*)(ws + (size_t)(((w * 2 + (d - 6)) * 8 + ks) * 64 + lane) * 16) = v;
                } else {
                    wregO[d - 6][ks] = v;
                }
            }
        }
    }
    if constexpr (USE_WS) {
        // ws stores must be visible before in-loop loads of same addresses
        asm volatile("s_waitcnt vmcnt(0)" ::: "memory");
    }

    // ---- h0 -> hlds[0] (bf16, XOR swizzle per row) ----
    {
        const int row  = tid >> 5;
        const int col0 = (tid & 31) * 8;
        const float* hp = h0 + (size_t)(g * 16 + row) * H_N + col0;
        const int sw = (row & 7) << 4;
#pragma unroll
        for (int j = 0; j < 8; ++j) {
            int byte = row * 512 + ((2 * (col0 + j)) ^ sw);
            *(short*)((char*)hlds[0] + byte) = f2bf(hp[j]);
        }
    }

    // ---- c0 -> registers ----
    float cst[2][4];
#pragma unroll
    for (int ct = 0; ct < 2; ++ct)
#pragma unroll
        for (int r = 0; r < 4; ++r)
            cst[ct][r] = c0[(size_t)(g * 16 + kg * 4 + r) * H_N + 32 * w + 16 * ct + l15];

    float hnew[2][4] = {};

    __syncthreads();

    const char* pxg  = out + (size_t)g * 16384 + (size_t)w * 1024 + (size_t)lane * 8;
    char* st_h = out + (size_t)(g * 16 + kg * 4) * 1024 + (size_t)(32 * w + l15) * 4;
    char* st_c = st_h + HY_BYTES;
    const char* wsb = ws + (size_t)w * 16384 + (size_t)lane * 16;

    const int amask = (l15 & 7) << 4;

    s16x4 xg[8];

#define XG_LOAD(T) do {                                                       \
        const char* _p = pxg + ((size_t)(T) << 16);                           \
        xg[0] = ntl4(_p);                   xg[1] = ntl4(_p + 512);           \
        xg[2] = ntl4(_p + 8192);            xg[3] = ntl4(_p + 8704);          \
        xg[4] = ntl4(_p + HY_BYTES);        xg[5] = ntl4(_p + HY_BYTES + 512);\
        xg[6] = ntl4(_p + HY_BYTES + 8192); xg[7] = ntl4(_p + HY_BYTES + 8704);\
    } while (0)

    XG_LOAD(0);   // prologue: xg for step 0 (compiler waits at first use)

#define STEP(PAR, T) do {                                                     \
        /* h,c of step T-1 -> global, CACHED stores (L2 ack, never waited) */ \
        if ((T) > 0) {                                                        \
            char* _hp = st_h + ((size_t)((T) - 1) << 16);                     \
            char* _cp = st_c + ((size_t)((T) - 1) << 16);                     \
            _Pragma("unroll")                                                 \
            for (int ct = 0; ct < 2; ++ct)                                    \
                _Pragma("unroll")                                             \
                for (int r = 0; r < 4; ++r) {                                 \
                    *(float*)(_hp + r * 1024 + ct * 64) = hnew[ct][r];        \
                    *(float*)(_cp + r * 1024 + ct * 64) = cst[ct][r];         \
                }                                                             \
        }                                                                     \
        /* acc <- xg fragment (identical layout); compiler inserts counted */ \
        /* vmcnt for these uses (stores above don't force a full drain) */    \
        f32x4 acc[8];                                                         \
        _Pragma("unroll")                                                     \
        for (int d = 0; d < 8; ++d) {                                         \
            acc[d][0] = bf2f(xg[d][0]); acc[d][1] = bf2f(xg[d][1]);           \
            acc[d][2] = bf2f(xg[d][2]); acc[d][3] = bf2f(xg[d][3]);           \
        }                                                                     \
        s16x8 bo0, bo1, bo2, bo3, bo4, bo5;                                   \
        if constexpr (USE_WS) {                                               \
            bo0 = *(const s16x8*)(wsb + 0 * 8192 + 0 * 1024);                 \
            bo1 = *(const s16x8*)(wsb + 1 * 8192 + 0 * 1024);                 \
            bo2 = *(const s16x8*)(wsb + 0 * 8192 + 1 * 1024);                 \
            bo3 = *(const s16x8*)(wsb + 1 * 8192 + 1 * 1024);                 \
            bo4 = *(const s16x8*)(wsb + 0 * 8192 + 2 * 1024);                 \
            bo5 = *(const s16x8*)(wsb + 1 * 8192 + 2 * 1024);                 \
        }                                                                     \
        _Pragma("unroll")                                                     \
        for (int ks = 0; ks < 8; ++ks) {                                      \
            s16x8 av = *(const s16x8*)((const char*)hlds[PAR] +               \
                            l15 * 512 + ((ks * 64 + kg * 16) ^ amask));       \
            acc[0] = MFMA(av, wreg[0][ks], acc[0]);                           \
            acc[1] = MFMA(av, wreg[1][ks], acc[1]);                           \
            acc[2] = MFMA(av, wreg[2][ks], acc[2]);                           \
            acc[3] = MFMA(av, wreg[3][ks], acc[3]);                           \
            s16x8 b4 = *(const s16x8*)(&wlds[(((w * 2 + 0) * 8 + ks) * 64 + lane) * 8]); \
            acc[4] = MFMA(av, b4, acc[4]);                                    \
            s16x8 b5 = *(const s16x8*)(&wlds[(((w * 2 + 1) * 8 + ks) * 64 + lane) * 8]); \
            acc[5] = MFMA(av, b5, acc[5]);                                    \
            if constexpr (USE_WS) {                                           \
                s16x8 c0r, c1r;                                               \
                if ((ks % 3) == 0)      { c0r = bo0; c1r = bo1; }             \
                else if ((ks % 3) == 1) { c0r = bo2; c1r = bo3; }             \
                else                    { c0r = bo4; c1r = bo5; }             \
                acc[6] = MFMA(av, c0r, acc[6]);                               \
                acc[7] = MFMA(av, c1r, acc[7]);                               \
                if (ks < 5) {                                                 \
                    s16x8 n0 = *(const s16x8*)(wsb + 0 * 8192 + (ks + 3) * 1024); \
                    s16x8 n1 = *(const s16x8*)(wsb + 1 * 8192 + (ks + 3) * 1024); \
                    if ((ks % 3) == 0)      { bo0 = n0; bo1 = n1; }           \
                    else if ((ks % 3) == 1) { bo2 = n0; bo3 = n1; }           \
                    else                    { bo4 = n0; bo5 = n1; }           \
                }                                                             \
            } else {                                                          \
                acc[6] = MFMA(av, wregO[0][ks], acc[6]);                      \
                acc[7] = MFMA(av, wregO[1][ks], acc[7]);                      \
            }                                                                 \
        }                                                                     \
        /* prefetch next xg AFTER MFMA (ws-ring waits never drain these); */  \
        /* activation + barrier (~1-2k cyc) covers HBM latency before use */  \
        if ((T) + 1 < T_N) XG_LOAD((T) + 1);                                  \
        _Pragma("unroll")                                                     \
        for (int ct = 0; ct < 2; ++ct) {                                      \
            _Pragma("unroll")                                                 \
            for (int r = 0; r < 4; ++r) {                                     \
                float zi = acc[0 + ct][r];                                    \
                float zf = acc[2 + ct][r];                                    \
                float zg = acc[4 + ct][r];                                    \
                float zo = acc[6 + ct][r];                                    \
                float Ei = e2c(-C1 * zi);                                     \
                float Ef = e2c(-C1 * zf);                                     \
                float Eg = e2c(-C2 * zg);                                     \
                float Eo = e2c(-C1 * zo);                                     \
                float ai = 1.0f + Ei, af = 1.0f + Ef;                         \
                float ag = 1.0f + Eg, ao = 1.0f + Eo;                         \
                float r1 = __builtin_amdgcn_rcpf(ai * af);                    \
                float gi = r1 * af;                                           \
                float gf = r1 * ai;                                           \
                float r2 = __builtin_amdgcn_rcpf(ag * ao);                    \
                float go = r2 * ag;                                           \
                float tg = 2.0f * (r2 * ao) - 1.0f;                           \
                float c  = gf * cst[ct][r] + gi * tg;                         \
                cst[ct][r] = c;                                               \
                float Ec = e2c(-C2 * c);                                      \
                float tc = 2.0f * __builtin_amdgcn_rcpf(1.0f + Ec) - 1.0f;    \
                hnew[ct][r] = go * tc;                                        \
            }                                                                 \
        }                                                                     \
        /* h -> hlds[PAR^1] (other buffer) */                                 \
        _Pragma("unroll")                                                     \
        for (int ct = 0; ct < 2; ++ct)                                        \
            _Pragma("unroll")                                                 \
            for (int r = 0; r < 4; ++r) {                                     \
                int row = kg * 4 + r;                                         \
                int col = 32 * w + 16 * ct + l15;                             \
                int byte = row * 512 + ((2 * col) ^ ((row & 7) << 4));        \
                *(short*)((char*)hlds[(PAR) ^ 1] + byte) = f2bf(hnew[ct][r]); \
            }                                                                 \
        /* single barrier: LDS visibility only — no vmem drain */             \
        asm volatile("s_waitcnt lgkmcnt(0)" ::: "memory");                    \
        __builtin_amdgcn_s_barrier();                                         \
        asm volatile("" ::: "memory");                                        \
    } while (0)

#pragma unroll 1
    for (int tt = 0; tt < T_N; tt += 2) {
        STEP(0, tt);
        STEP(1, tt + 1);
    }

    // epilogue: h,c of last step + final (hy[-1], cy[-1])
    {
        char* hp = st_h + ((size_t)(T_N - 1) << 16);
        char* cp = st_c + ((size_t)(T_N - 1) << 16);
        char* fh = out + 2 * HY_BYTES + (size_t)(g * 16 + kg * 4) * 1024 + (size_t)(32 * w + l15) * 4;
        char* fc = fh + 65536;
#pragma unroll
        for (int ct = 0; ct < 2; ++ct)
#pragma unroll
            for (int r = 0; r < 4; ++r) {
                *(float*)(hp + r * 1024 + ct * 64) = hnew[ct][r];
                *(float*)(cp + r * 1024 + ct * 64) = cst[ct][r];
                *(float*)(fh + r * 1024 + ct * 64) = hnew[ct][r];
                *(float*)(fc + r * 1024 + ct * 64) = cst[ct][r];
            }
    }
#undef STEP
#undef XG_LOAD
}

extern "C" void kernel_launch(void* const* d_in, const int* in_sizes, int n_in,
                              void* d_out, int out_size, void* d_ws, size_t ws_size,
                              hipStream_t stream) {
    (void)in_sizes; (void)n_in; (void)out_size;
    const float* x    = (const float*)d_in[0];
    const float* h0   = (const float*)d_in[1];
    const float* c0   = (const float*)d_in[2];
    const float* w_ih = (const float*)d_in[3];
    const float* w_hh = (const float*)d_in[4];
    const float* b_ih = (const float*)d_in[5];
    const float* b_hh = (const float*)d_in[6];
    char* out = (char*)d_out;

    xg_gemm<<<dim3(1024, 4), 512, 0, stream>>>(x, w_ih, b_ih, b_hh, out);
    if (ws_size >= 131072) {
        lstm_rec<true><<<4, 512, 0, stream>>>(h0, c0, w_hh, out, (char*)d_ws);
    } else {
        lstm_rec<false><<<4, 512, 0, stream>>>(h0, c0, w_hh, out, (char*)d_ws);
    }
}

// Round 7
// 9705.218 us; speedup vs baseline: 1.0164x; 1.0164x over previous
//
#include <hip/hip_runtime.h>

typedef short s16x8 __attribute__((ext_vector_type(8)));
typedef short s16x4 __attribute__((ext_vector_type(4)));
typedef float f32x4 __attribute__((ext_vector_type(4)));

#define T_N 2048
#define B_N 64
#define H_N 256
#define I_N 256
#define HY_BYTES ((size_t)134217728)   // 4 * T * B * H
#define EXCH_BYTES 65536               // u64[2 parity][8 wg][8 wave][64 lane]

static __device__ __forceinline__ short f2bf(float f) {
    unsigned u = __builtin_bit_cast(unsigned, f);
    u += 0x7FFFu + ((u >> 16) & 1u);   // RNE
    return (short)(u >> 16);
}
static __device__ __forceinline__ float bf2f(short h) {
    unsigned u = ((unsigned)(unsigned short)h) << 16;
    return __builtin_bit_cast(float, u);
}
static __device__ __forceinline__ float e2c(float a) {
    return __builtin_amdgcn_exp2f(fminf(a, 126.0f));
}
static __device__ __forceinline__ s16x4 ntl4(const void* p) {
    return __builtin_nontemporal_load((const s16x4*)p);
}

#define C1 1.44269504088896340f   // log2(e)
#define C2 2.88539008177792681f   // 2*log2(e)

#define MFMA(a, b, c) __builtin_amdgcn_mfma_f32_16x16x32_bf16(a, b, c, 0, 0, 0)

// ---------------------------------------------------------------------------
// Phase 0: zero the exchange flags in ws (ws is not re-poisoned per replay).
// ---------------------------------------------------------------------------
__global__ void zero_flags(char* __restrict__ ws) {
    if (threadIdx.x < 16) ((unsigned*)(ws + EXCH_BYTES))[threadIdx.x] = 0u;
}

// ---------------------------------------------------------------------------
// Phase 1: xg = x @ w_ih^T + bias, PRE-SCALED by -C1 (i,f,o) / -C2 (g) so the
// recurrence feeds exp2 directly.  Stored bf16 in MFMA C-fragment layout
// inside d_out (layout unchanged from prior rounds).
// ---------------------------------------------------------------------------
__global__ __launch_bounds__(512) void xg_gemm(
        const float* __restrict__ x, const float* __restrict__ w_ih,
        const float* __restrict__ b_ih, const float* __restrict__ b_hh,
        char* __restrict__ out)
{
    const int tid  = threadIdx.x;
    const int wave = tid >> 6;
    const int lane = tid & 63;
    const int l15  = lane & 15;
    const int kg   = lane >> 4;

    __shared__ short Blds[8192];

    const int m16 = blockIdx.x * 8 + wave;
    const int by  = blockIdx.y;
    const int n0  = by * 256;

    const float* xrow = x + (size_t)(m16 * 16 + l15) * I_N;

    f32x4 acc[16] = {};

#pragma unroll 1
    for (int ks = 0; ks < 8; ++ks) {
        __syncthreads();
#pragma unroll
        for (int h = 0; h < 2; ++h) {
            int nl = (tid >> 2) + h * 128;
            int c  = tid & 3;
            const float* wp = w_ih + (size_t)(n0 + nl) * I_N + ks * 32 + c * 8;
            f32x4 w0 = *(const f32x4*)(wp);
            f32x4 w1 = *(const f32x4*)(wp + 4);
            s16x8 bv;
            bv[0]=f2bf(w0[0]); bv[1]=f2bf(w0[1]); bv[2]=f2bf(w0[2]); bv[3]=f2bf(w0[3]);
            bv[4]=f2bf(w1[0]); bv[5]=f2bf(w1[1]); bv[6]=f2bf(w1[2]); bv[7]=f2bf(w1[3]);
            int dt = nl >> 4;
            int lp = (nl & 15) + 16 * c;
            *(s16x8*)(&Blds[(dt * 64 + lp) * 8]) = bv;
        }
        __syncthreads();
        const float* ap = xrow + ks * 32 + kg * 8;
        f32x4 a0 = *(const f32x4*)(ap);
        f32x4 a1 = *(const f32x4*)(ap + 4);
        s16x8 av;
        av[0]=f2bf(a0[0]); av[1]=f2bf(a0[1]); av[2]=f2bf(a0[2]); av[3]=f2bf(a0[3]);
        av[4]=f2bf(a1[0]); av[5]=f2bf(a1[1]); av[6]=f2bf(a1[2]); av[7]=f2bf(a1[3]);
#pragma unroll
        for (int dt = 0; dt < 16; ++dt) {
            s16x8 bv = *(const s16x8*)(&Blds[(dt * 64 + lane) * 8]);
            acc[dt] = MFMA(av, bv, acc[dt]);
        }
    }

    const int t = m16 >> 2;
    const int g = m16 & 3;
#pragma unroll
    for (int dt = 0; dt < 16; ++dt) {
        int tau = by * 16 + dt;
        int n   = tau * 16 + l15;
        float bias = b_ih[n] + b_hh[n];
        float scale = ((tau >> 4) == 2) ? -C2 : -C1;   // g-gate vs i,f,o
        size_t base = (tau < 32)
            ? ((size_t)t * 65536 + (size_t)g * 16384 + (size_t)tau * 512)
            : (HY_BYTES + (size_t)t * 65536 + (size_t)g * 16384 + (size_t)(tau - 32) * 512);
        s16x4 o;
        o[0] = f2bf(scale * (acc[dt][0] + bias));
        o[1] = f2bf(scale * (acc[dt][1] + bias));
        o[2] = f2bf(scale * (acc[dt][2] + bias));
        o[3] = f2bf(scale * (acc[dt][3] + bias));
        *(s16x4*)(out + base + lane * 8) = o;
    }
}

// ---------------------------------------------------------------------------
// Phase 2: 8 WGs on 8 CUs.  WG b: batch group g=b&3, H-half hf=b>>2.
// Wave w owns col-tile tc=hf*8+w (4 gate tiles, W register-resident,
// pre-scaled by -C1/-C2).  Per step the two WGs of a group exchange h-halves
// through d_ws (relaxed agent atomics; exch stores drained by vmcnt(0) before
// the flag RMW).  Poll has a STICKY BOUNDED TIMEOUT: a broken protocol
// produces a fast absmax failure, never a hung container.
// ---------------------------------------------------------------------------
__global__ __launch_bounds__(512)
__attribute__((amdgpu_waves_per_eu(2, 2)))
void lstm_rec8(
        const float* __restrict__ h0, const float* __restrict__ c0,
        const float* __restrict__ w_hh, char* __restrict__ out,
        char* __restrict__ ws)
{
    const int b    = blockIdx.x;       // 0..7
    const int g    = b & 3;
    const int hf   = b >> 2;
    const int tid  = threadIdx.x;
    const int w    = tid >> 6;
    const int lane = tid & 63;
    const int l15  = lane & 15;
    const int kg   = lane >> 4;

    const int tc   = hf * 8 + w;       // my col-tile (0..15)
    const int ptc  = (hf ^ 1) * 8 + w; // partner col-tile staged by this wave
    const int col  = tc * 16 + l15;
    const int pcol = ptc * 16 + l15;

    __shared__ short hlds[2][4096];    // double-buffered 16x256 bf16, swizzled

    unsigned long long* exch = (unsigned long long*)ws;
    unsigned* flags = (unsigned*)(ws + EXCH_BYTES);
    const size_t myx = ((size_t)b * 8 + w) * 64 + lane;
    const size_t pbx = ((size_t)(b ^ 4) * 8 + w) * 64 + lane;
    unsigned* myflag = &flags[b];
    unsigned* pflag  = &flags[b ^ 4];

    // ---- W fragments: 4 gate tiles, pre-scaled, all in registers ----
    s16x8 wreg[4][8];
#pragma unroll
    for (int q = 0; q < 4; ++q) {
        const int tau = 16 * q + tc;
        const float scale = (q == 2) ? -C2 : -C1;
        const float* wp = w_hh + (size_t)(tau * 16 + l15) * H_N;
#pragma unroll
        for (int ks = 0; ks < 8; ++ks) {
            const float* p = wp + ks * 32 + kg * 8;
            f32x4 w0 = *(const f32x4*)(p);
            f32x4 w1 = *(const f32x4*)(p + 4);
            s16x8 v;
            v[0]=f2bf(scale*w0[0]); v[1]=f2bf(scale*w0[1]);
            v[2]=f2bf(scale*w0[2]); v[3]=f2bf(scale*w0[3]);
            v[4]=f2bf(scale*w1[0]); v[5]=f2bf(scale*w1[1]);
            v[6]=f2bf(scale*w1[2]); v[7]=f2bf(scale*w1[3]);
            wreg[q][ks] = v;
        }
    }

    // ---- h0 -> hlds[0] (full 256 cols, bf16, XOR swizzle per row) ----
    {
        const int row  = tid >> 5;
        const int col0 = (tid & 31) * 8;
        const float* hp = h0 + (size_t)(g * 16 + row) * H_N + col0;
        const int sw = (row & 7) << 4;
#pragma unroll
        for (int j = 0; j < 8; ++j) {
            int byte = row * 512 + ((2 * (col0 + j)) ^ sw);
            *(short*)((char*)hlds[0] + byte) = f2bf(hp[j]);
        }
    }

    // ---- c0 -> registers (my cols only) ----
    float cst[4];
#pragma unroll
    for (int r = 0; r < 4; ++r)
        cst[r] = c0[(size_t)(g * 16 + kg * 4 + r) * H_N + col];

    float hnew[4] = {};
    unsigned dead = 0;    // sticky poll-timeout marker

    __syncthreads();

    const char* p_xg0 = out + (size_t)g * 16384 + (size_t)tc * 512 + (size_t)lane * 8;           // i
    const char* p_xg1 = p_xg0 + 16 * 512;                                                         // f
    const char* p_xg2 = out + HY_BYTES + (size_t)g * 16384 + (size_t)tc * 512 + (size_t)lane * 8; // g
    const char* p_xg3 = p_xg2 + 16 * 512;                                                         // o
    char* st_h = out + (size_t)(g * 16 + kg * 4) * 1024 + (size_t)col * 4;
    char* st_c = st_h + HY_BYTES;

    const int amask = (l15 & 7) << 4;

    s16x4 xg[4];

#define XG_LOAD(T) do {                                                       \
        const size_t _o = ((size_t)(T) << 16);                                \
        xg[0] = ntl4(p_xg0 + _o);  xg[1] = ntl4(p_xg1 + _o);                  \
        xg[2] = ntl4(p_xg2 + _o);  xg[3] = ntl4(p_xg3 + _o);                  \
    } while (0)

    XG_LOAD(0);
    asm volatile("s_waitcnt vmcnt(0)" ::: "memory");

#define STEP(PAR, T) do {                                                     \
        /* h,c outputs of step T-1 (cached stores; never waited on) */        \
        if ((T) > 0) {                                                        \
            char* _hp = st_h + ((size_t)((T) - 1) << 16);                     \
            char* _cp = st_c + ((size_t)((T) - 1) << 16);                     \
            _Pragma("unroll")                                                 \
            for (int r = 0; r < 4; ++r) {                                     \
                *(float*)(_hp + r * 1024) = hnew[r];                          \
                *(float*)(_cp + r * 1024) = cst[r];                           \
            }                                                                 \
        }                                                                     \
        /* acc <- pre-scaled xg fragment (identical layout) */                \
        f32x4 acc[4];                                                         \
        _Pragma("unroll")                                                     \
        for (int q = 0; q < 4; ++q) {                                         \
            acc[q][0] = bf2f(xg[q][0]); acc[q][1] = bf2f(xg[q][1]);           \
            acc[q][2] = bf2f(xg[q][2]); acc[q][3] = bf2f(xg[q][3]);           \
        }                                                                     \
        /* gates += h_{T-1} @ (scaled W)^T  (full k=256; W in regs) */        \
        _Pragma("unroll")                                                     \
        for (int ks = 0; ks < 8; ++ks) {                                      \
            s16x8 av = *(const s16x8*)((const char*)hlds[PAR] +               \
                            l15 * 512 + ((ks * 64 + kg * 16) ^ amask));       \
            acc[0] = MFMA(av, wreg[0][ks], acc[0]);                           \
            acc[1] = MFMA(av, wreg[1][ks], acc[1]);                           \
            acc[2] = MFMA(av, wreg[2][ks], acc[2]);                           \
            acc[3] = MFMA(av, wreg[3][ks], acc[3]);                           \
        }                                                                     \
        /* activations (exp2 fed directly by pre-scaled gates) */             \
        unsigned pk0, pk1;                                                    \
        {                                                                     \
            _Pragma("unroll")                                                 \
            for (int r = 0; r < 4; ++r) {                                     \
                float Ei = e2c(acc[0][r]);                                    \
                float Ef = e2c(acc[1][r]);                                    \
                float Eg = e2c(acc[2][r]);                                    \
                float Eo = e2c(acc[3][r]);                                    \
                float ai = 1.0f + Ei, af = 1.0f + Ef;                         \
                float ag = 1.0f + Eg, ao = 1.0f + Eo;                         \
                float r1 = __builtin_amdgcn_rcpf(ai * af);                    \
                float gi = r1 * af;                                           \
                float gf = r1 * ai;                                           \
                float r2 = __builtin_amdgcn_rcpf(ag * ao);                    \
                float go = r2 * ag;                                           \
                float tg = 2.0f * (r2 * ao) - 1.0f;                           \
                float c  = gf * cst[r] + gi * tg;                             \
                cst[r] = c;                                                   \
                float Ec = e2c(-C2 * c);                                      \
                float tc_ = 2.0f * __builtin_amdgcn_rcpf(1.0f + Ec) - 1.0f;   \
                hnew[r] = go * tc_;                                           \
            }                                                                 \
            unsigned s0 = (unsigned short)f2bf(hnew[0]);                      \
            unsigned s1 = (unsigned short)f2bf(hnew[1]);                      \
            unsigned s2 = (unsigned short)f2bf(hnew[2]);                      \
            unsigned s3 = (unsigned short)f2bf(hnew[3]);                      \
            pk0 = s0 | (s1 << 16);                                            \
            pk1 = s2 | (s3 << 16);                                            \
            /* own-half h -> hlds[PAR^1] */                                   \
            _Pragma("unroll")                                                 \
            for (int r = 0; r < 4; ++r) {                                     \
                int row = kg * 4 + r;                                         \
                int byte = row * 512 + ((2 * col) ^ ((row & 7) << 4));        \
                unsigned v = (r < 2) ? pk0 : pk1;                             \
                *(short*)((char*)hlds[(PAR) ^ 1] + byte) =                    \
                    (short)((r & 1) ? (v >> 16) : v);                         \
            }                                                                 \
        }                                                                     \
        if ((T) + 1 < T_N) {                                                  \
            /* publish my 4 values (coherence point), drain, then flag */     \
            unsigned long long val = ((unsigned long long)pk1 << 32) | pk0;   \
            __hip_atomic_store(exch + (size_t)(PAR) * 4096 + myx, val,        \
                               __ATOMIC_RELAXED, __HIP_MEMORY_SCOPE_AGENT);   \
            asm volatile("s_waitcnt vmcnt(0)" ::: "memory");                  \
            if (lane == 0)                                                    \
                __hip_atomic_fetch_add(myflag, 1u, __ATOMIC_RELAXED,          \
                                       __HIP_MEMORY_SCOPE_AGENT);             \
        }                                                                     \
        /* prefetch next step's xg */                                         \
        if ((T) + 1 < T_N) XG_LOAD((T) + 1);                                  \
        if ((T) + 1 < T_N) {                                                  \
            /* partner half: bounded poll, read, stage into hlds[PAR^1] */    \
            const unsigned tgt = 8u * ((T) + 1);                              \
            if (!dead) {                                                      \
                unsigned spins = 0;                                           \
                while (__hip_atomic_load(pflag, __ATOMIC_RELAXED,             \
                                         __HIP_MEMORY_SCOPE_AGENT) < tgt) {   \
                    __builtin_amdgcn_s_sleep(2);                              \
                    if (++spins > 16384u) { dead = 1; break; }                \
                }                                                             \
            }                                                                 \
            unsigned long long pv = __hip_atomic_load(                        \
                exch + (size_t)(PAR) * 4096 + pbx,                            \
                __ATOMIC_RELAXED, __HIP_MEMORY_SCOPE_AGENT);                  \
            _Pragma("unroll")                                                 \
            for (int r = 0; r < 4; ++r) {                                     \
                int row = kg * 4 + r;                                         \
                int byte = row * 512 + ((2 * pcol) ^ ((row & 7) << 4));       \
                *(short*)((char*)hlds[(PAR) ^ 1] + byte) =                    \
                    (short)(pv >> (16 * r));                                  \
            }                                                                 \
        }                                                                     \
        /* single barrier per step: all LDS writes visible */                 \
        asm volatile("s_waitcnt lgkmcnt(0)" ::: "memory");                    \
        __builtin_amdgcn_s_barrier();                                         \
        asm volatile("" ::: "memory");                                        \
    } while (0)

#pragma unroll 1
    for (int tt = 0; tt < T_N; tt += 2) {
        STEP(0, tt);
        STEP(1, tt + 1);
    }

    // epilogue: h,c of last step + final (hy[-1], cy[-1]) for my cols
    {
        char* hp = st_h + ((size_t)(T_N - 1) << 16);
        char* cp = st_c + ((size_t)(T_N - 1) << 16);
        char* fh = out + 2 * HY_BYTES + (size_t)(g * 16 + kg * 4) * 1024 + (size_t)col * 4;
        char* fc = fh + 65536;
#pragma unroll
        for (int r = 0; r < 4; ++r) {
            *(float*)(hp + r * 1024) = hnew[r];
            *(float*)(cp + r * 1024) = cst[r];
            *(float*)(fh + r * 1024) = hnew[r];
            *(float*)(fc + r * 1024) = cst[r];
        }
    }
#undef STEP
#undef XG_LOAD
}

// ---------------------------------------------------------------------------
// Fallback (ws too small): round-5 4-WG kernel, updated for pre-scaled xg/W.
// ---------------------------------------------------------------------------
__global__ __launch_bounds__(512)
__attribute__((amdgpu_waves_per_eu(2, 2)))
void lstm_rec_old(
        const float* __restrict__ h0, const float* __restrict__ c0,
        const float* __restrict__ w_hh, char* __restrict__ out)
{
    const int g    = blockIdx.x;
    const int tid  = threadIdx.x;
    const int w    = tid >> 6;
    const int lane = tid & 63;
    const int l15  = lane & 15;
    const int kg   = lane >> 4;

    __shared__ short hlds[2][4096];
    __shared__ short wlds[65536];

    s16x8 wreg[4][8];
    s16x8 wregO[2][8];

#pragma unroll
    for (int d = 0; d < 8; ++d) {
        const int q = d >> 1, ct = d & 1;
        const int tau = 16 * q + 2 * w + ct;
        const float scale = (q == 2) ? -C2 : -C1;
        const float* wp = w_hh + (size_t)(tau * 16 + l15) * H_N;
#pragma unroll
        for (int ks = 0; ks < 8; ++ks) {
            const float* p = wp + ks * 32 + kg * 8;
            f32x4 w0 = *(const f32x4*)(p);
            f32x4 w1 = *(const f32x4*)(p + 4);
            s16x8 v;
            v[0]=f2bf(scale*w0[0]); v[1]=f2bf(scale*w0[1]);
            v[2]=f2bf(scale*w0[2]); v[3]=f2bf(scale*w0[3]);
            v[4]=f2bf(scale*w1[0]); v[5]=f2bf(scale*w1[1]);
            v[6]=f2bf(scale*w1[2]); v[7]=f2bf(scale*w1[3]);
            if (d < 4)      wreg[d][ks] = v;
            else if (d < 6) *(s16x8*)(&wlds[(((w * 2 + (d - 4)) * 8 + ks) * 64 + lane) * 8]) = v;
            else            wregO[d - 6][ks] = v;
        }
    }

    {
        const int row  = tid >> 5;
        const int col0 = (tid & 31) * 8;
        const float* hp = h0 + (size_t)(g * 16 + row) * H_N + col0;
        const int sw = (row & 7) << 4;
#pragma unroll
        for (int j = 0; j < 8; ++j) {
            int byte = row * 512 + ((2 * (col0 + j)) ^ sw);
            *(short*)((char*)hlds[0] + byte) = f2bf(hp[j]);
        }
    }

    float cst[2][4];
#pragma unroll
    for (int ct = 0; ct < 2; ++ct)
#pragma unroll
        for (int r = 0; r < 4; ++r)
            cst[ct][r] = c0[(size_t)(g * 16 + kg * 4 + r) * H_N + 32 * w + 16 * ct + l15];

    float hnew[2][4] = {};
    __syncthreads();

    const char* pxg  = out + (size_t)g * 16384 + (size_t)w * 1024 + (size_t)lane * 8;
    char* st_h = out + (size_t)(g * 16 + kg * 4) * 1024 + (size_t)(32 * w + l15) * 4;
    char* st_c = st_h + HY_BYTES;
    const int amask = (l15 & 7) << 4;

    s16x4 xg[8];
#define XG_LOAD(T) do {                                                       \
        const char* _p = pxg + ((size_t)(T) << 16);                           \
        xg[0] = ntl4(_p);                   xg[1] = ntl4(_p + 512);           \
        xg[2] = ntl4(_p + 8192);            xg[3] = ntl4(_p + 8704);          \
        xg[4] = ntl4(_p + HY_BYTES);        xg[5] = ntl4(_p + HY_BYTES + 512);\
        xg[6] = ntl4(_p + HY_BYTES + 8192); xg[7] = ntl4(_p + HY_BYTES + 8704);\
    } while (0)

    XG_LOAD(0);
    asm volatile("s_waitcnt vmcnt(0)" ::: "memory");

#pragma unroll 1
    for (int t = 0; t < T_N; ++t) {
        const int PAR = t & 1;
        if (t > 0) {
            char* _hp = st_h + ((size_t)(t - 1) << 16);
            char* _cp = st_c + ((size_t)(t - 1) << 16);
#pragma unroll
            for (int ct = 0; ct < 2; ++ct)
#pragma unroll
                for (int r = 0; r < 4; ++r) {
                    *(float*)(_hp + r * 1024 + ct * 64) = hnew[ct][r];
                    *(float*)(_cp + r * 1024 + ct * 64) = cst[ct][r];
                }
        }
        f32x4 acc[8];
#pragma unroll
        for (int d = 0; d < 8; ++d) {
            acc[d][0] = bf2f(xg[d][0]); acc[d][1] = bf2f(xg[d][1]);
            acc[d][2] = bf2f(xg[d][2]); acc[d][3] = bf2f(xg[d][3]);
        }
#pragma unroll
        for (int ks = 0; ks < 8; ++ks) {
            s16x8 av = *(const s16x8*)((const char*)hlds[PAR] +
                            l15 * 512 + ((ks * 64 + kg * 16) ^ amask));
            acc[0] = MFMA(av, wreg[0][ks], acc[0]);
            acc[1] = MFMA(av, wreg[1][ks], acc[1]);
            acc[2] = MFMA(av, wreg[2][ks], acc[2]);
            acc[3] = MFMA(av, wreg[3][ks], acc[3]);
            s16x8 b4 = *(const s16x8*)(&wlds[(((w * 2 + 0) * 8 + ks) * 64 + lane) * 8]);
            acc[4] = MFMA(av, b4, acc[4]);
            s16x8 b5 = *(const s16x8*)(&wlds[(((w * 2 + 1) * 8 + ks) * 64 + lane) * 8]);
            acc[5] = MFMA(av, b5, acc[5]);
            acc[6] = MFMA(av, wregO[0][ks], acc[6]);
            acc[7] = MFMA(av, wregO[1][ks], acc[7]);
        }
        if (t + 1 < T_N) XG_LOAD(t + 1);
#pragma unroll
        for (int ct = 0; ct < 2; ++ct)
#pragma unroll
            for (int r = 0; r < 4; ++r) {
                float Ei = e2c(acc[0 + ct][r]), Ef = e2c(acc[2 + ct][r]);
                float Eg = e2c(acc[4 + ct][r]), Eo = e2c(acc[6 + ct][r]);
                float ai = 1.0f + Ei, af = 1.0f + Ef;
                float ag = 1.0f + Eg, ao = 1.0f + Eo;
                float r1 = __builtin_amdgcn_rcpf(ai * af);
                float gi = r1 * af, gf = r1 * ai;
                float r2 = __builtin_amdgcn_rcpf(ag * ao);
                float go = r2 * ag;
                float tg = 2.0f * (r2 * ao) - 1.0f;
                float c  = gf * cst[ct][r] + gi * tg;
                cst[ct][r] = c;
                float Ec = e2c(-C2 * c);
                float tcv = 2.0f * __builtin_amdgcn_rcpf(1.0f + Ec) - 1.0f;
                hnew[ct][r] = go * tcv;
            }
#pragma unroll
        for (int ct = 0; ct < 2; ++ct)
#pragma unroll
            for (int r = 0; r < 4; ++r) {
                int row = kg * 4 + r;
                int c2 = 32 * w + 16 * ct + l15;
                int byte = row * 512 + ((2 * c2) ^ ((row & 7) << 4));
                *(short*)((char*)hlds[PAR ^ 1] + byte) = f2bf(hnew[ct][r]);
            }
        asm volatile("s_waitcnt lgkmcnt(0)" ::: "memory");
        __builtin_amdgcn_s_barrier();
        asm volatile("" ::: "memory");
    }
    {
        char* hp = st_h + ((size_t)(T_N - 1) << 16);
        char* cp = st_c + ((size_t)(T_N - 1) << 16);
        char* fh = out + 2 * HY_BYTES + (size_t)(g * 16 + kg * 4) * 1024 + (size_t)(32 * w + l15) * 4;
        char* fc = fh + 65536;
#pragma unroll
        for (int ct = 0; ct < 2; ++ct)
#pragma unroll
            for (int r = 0; r < 4; ++r) {
                *(float*)(hp + r * 1024 + ct * 64) = hnew[ct][r];
                *(float*)(cp + r * 1024 + ct * 64) = cst[ct][r];
                *(float*)(fh + r * 1024 + ct * 64) = hnew[ct][r];
                *(float*)(fc + r * 1024 + ct * 64) = cst[ct][r];
            }
    }
#undef XG_LOAD
}

extern "C" void kernel_launch(void* const* d_in, const int* in_sizes, int n_in,
                              void* d_out, int out_size, void* d_ws, size_t ws_size,
                              hipStream_t stream) {
    (void)in_sizes; (void)n_in; (void)out_size;
    const float* x    = (const float*)d_in[0];
    const float* h0   = (const float*)d_in[1];
    const float* c0   = (const float*)d_in[2];
    const float* w_ih = (const float*)d_in[3];
    const float* w_hh = (const float*)d_in[4];
    const float* b_ih = (const float*)d_in[5];
    const float* b_hh = (const float*)d_in[6];
    char* out = (char*)d_out;

    if (ws_size >= EXCH_BYTES + 64) {
        zero_flags<<<1, 64, 0, stream>>>((char*)d_ws);
        xg_gemm<<<dim3(1024, 4), 512, 0, stream>>>(x, w_ih, b_ih, b_hh, out);
        lstm_rec8<<<8, 512, 0, stream>>>(h0, c0, w_hh, out, (char*)d_ws);
    } else {
        xg_gemm<<<dim3(1024, 4), 512, 0, stream>>>(x, w_ih, b_ih, b_hh, out);
        lstm_rec_old<<<4, 512, 0, stream>>>(h0, c0, w_hh, out);
    }
}